// Round 1
// baseline (591.614 us; speedup 1.0000x reference)
//
#include <hip/hip_runtime.h>

#define D_DIM 128
#define DE_DIM 64
#define H_NUM 4
#define LN_EPS 1e-5f
#define LEAKY 0.2f

static __device__ __forceinline__ void atomicMaxF(float* addr, float v) {
  if (v >= 0.f) atomicMax((int*)addr, __float_as_int(v));
  else atomicMin((unsigned int*)addr, (unsigned int)__float_as_int(v));
}

__global__ void init_md_kernel(float* __restrict__ m, float* __restrict__ denom, int n4) {
  int i = blockIdx.x * blockDim.x + threadIdx.x;
  if (i < n4) { m[i] = -1e30f; denom[i] = 0.f; }
}

// a1[n,hd] = h[n] . W_att[0:128, hd]  ; a2[n,hd] = h[n] . W_att[128:256, hd]
__global__ __launch_bounds__(256) void node_att_kernel(
    const float* __restrict__ h, const float* __restrict__ W_att,
    float* __restrict__ a12, int N)
{
  int lane = threadIdx.x & 63;
  int wid = (int)((blockIdx.x * (long long)blockDim.x + threadIdx.x) >> 6);
  if (wid >= N) return;
  const float* hr = &h[(long long)wid * D_DIM];
  float h0 = hr[lane], h1 = hr[64 + lane];
  float p[8];
#pragma unroll
  for (int hd = 0; hd < 4; ++hd) {
    p[hd]     = h0 * W_att[lane * 4 + hd]         + h1 * W_att[(64 + lane) * 4 + hd];
    p[4 + hd] = h0 * W_att[(128 + lane) * 4 + hd] + h1 * W_att[(192 + lane) * 4 + hd];
  }
#pragma unroll
  for (int j = 0; j < 8; ++j) {
    float v = p[j];
#pragma unroll
    for (int off = 32; off; off >>= 1) v += __shfl_xor(v, off);
    if (lane == 0) a12[(long long)wid * 8 + j] = v;
  }
}

// Fused: x = ef@W_rel + b_rel ; LayerNorm ; ReLU ; u_part = wef@Wa3 ;
// u = leaky(a1[dst]+a2[src]+u_part+b_att) ; store u ; atomicMax m[dst]
__global__ __launch_bounds__(128) void edge_pass1_kernel(
    const float* __restrict__ edge_feat, const int* __restrict__ src, const int* __restrict__ dst,
    const float* __restrict__ W_rel, const float* __restrict__ b_rel,
    const float* __restrict__ ln_g, const float* __restrict__ ln_b,
    const float* __restrict__ W_att, const float* __restrict__ b_att,
    const float* __restrict__ a12,
    float* __restrict__ u_buf, float* __restrict__ m_buf, int E)
{
  __shared__ float ef_lds[2][64 * 65];   // +1 pad: conflict-free row reads
  int wv = threadIdx.x >> 6;
  int lane = threadIdx.x & 63;
  long long e0 = ((long long)blockIdx.x * 2 + wv) * 64;
  float* lds = ef_lds[wv];

  {
    int rb = lane >> 4;            // 0..3
    int c4 = (lane & 15) * 4;
#pragma unroll
    for (int it = 0; it < 16; ++it) {
      int r = it * 4 + rb;
      long long e = e0 + r;
      float4 v = make_float4(0.f, 0.f, 0.f, 0.f);
      if (e < E) v = *reinterpret_cast<const float4*>(&edge_feat[e * DE_DIM + c4]);
      float* p = &lds[r * 65 + c4];
      p[0] = v.x; p[1] = v.y; p[2] = v.z; p[3] = v.w;
    }
  }
  __syncthreads();

  long long e = e0 + lane;
  float x[D_DIM];
#pragma unroll
  for (int d = 0; d < D_DIM; ++d) x[d] = b_rel[d];
  for (int k = 0; k < DE_DIM; ++k) {
    float s = lds[lane * 65 + k];
    const float* w = &W_rel[k * D_DIM];   // wave-uniform -> s_load
#pragma unroll
    for (int d = 0; d < D_DIM; ++d) x[d] = fmaf(s, w[d], x[d]);
  }
  float sum = 0.f;
#pragma unroll
  for (int d = 0; d < D_DIM; ++d) sum += x[d];
  float mu = sum * (1.f / D_DIM);
  float sq = 0.f;
#pragma unroll
  for (int d = 0; d < D_DIM; ++d) { float c = x[d] - mu; sq += c * c; }
  float rstd = rsqrtf(sq * (1.f / D_DIM) + LN_EPS);
  float u[4] = {0.f, 0.f, 0.f, 0.f};
#pragma unroll
  for (int d = 0; d < D_DIM; ++d) {
    float wef = (x[d] - mu) * rstd * ln_g[d] + ln_b[d];
    wef = fmaxf(wef, 0.f);
#pragma unroll
    for (int hd = 0; hd < 4; ++hd) u[hd] = fmaf(wef, W_att[(256 + d) * 4 + hd], u[hd]);
  }
  if (e < E) {
    int sN = src[e], dN = dst[e];
    const float* ad = &a12[(long long)dN * 8];
    const float* as = &a12[(long long)sN * 8 + 4];
    float4 uo;
    float* up = &uo.x;
#pragma unroll
    for (int hd = 0; hd < 4; ++hd) {
      float v = ad[hd] + as[hd] + u[hd] + b_att[hd];
      v = (v >= 0.f) ? v : LEAKY * v;
      up[hd] = v;
      atomicMaxF(&m_buf[(long long)dN * 4 + hd], v);
    }
    *reinterpret_cast<float4*>(&u_buf[e * 4]) = uo;
  }
}

__global__ __launch_bounds__(256) void edge_pass2_kernel(
    const int* __restrict__ dst, float* __restrict__ u_buf,
    const float* __restrict__ m_buf, float* __restrict__ denom, int E)
{
  int e = blockIdx.x * blockDim.x + threadIdx.x;
  if (e >= E) return;
  int dN = dst[e];
  float4 uv = *reinterpret_cast<float4*>(&u_buf[(long long)e * 4]);
  float4 mv = *reinterpret_cast<const float4*>(&m_buf[(long long)dN * 4]);
  float4 ev;
  ev.x = __expf(uv.x - mv.x);
  ev.y = __expf(uv.y - mv.y);
  ev.z = __expf(uv.z - mv.z);
  ev.w = __expf(uv.w - mv.w);
  *reinterpret_cast<float4*>(&u_buf[(long long)e * 4]) = ev;
  float* dn = &denom[(long long)dN * 4];
  atomicAdd(&dn[0], ev.x); atomicAdd(&dn[1], ev.y);
  atomicAdd(&dn[2], ev.z); atomicAdd(&dn[3], ev.w);
}

// t[dst, hd*128 + d] += alpha[hd] * h[src, d]   (wave per edge)
__global__ __launch_bounds__(256) void edge_pass3_kernel(
    const float* __restrict__ h, const int* __restrict__ src, const int* __restrict__ dst,
    const float* __restrict__ u_buf, const float* __restrict__ denom,
    float* __restrict__ t, int E)
{
  int lane = threadIdx.x & 63;
  int e = (int)((blockIdx.x * (long long)blockDim.x + threadIdx.x) >> 6);
  if (e >= E) return;
  int sN = src[e], dN = dst[e];
  float4 ev = *reinterpret_cast<const float4*>(&u_buf[(long long)e * 4]);
  float4 dn = *reinterpret_cast<const float4*>(&denom[(long long)dN * 4]);
  float al[4] = {ev.x / dn.x, ev.y / dn.y, ev.z / dn.z, ev.w / dn.w};
  const float* hs = &h[(long long)sN * D_DIM];
  float h0 = hs[lane], h1 = hs[64 + lane];
  float* tb = &t[(long long)dN * 512];
#pragma unroll
  for (int hd = 0; hd < 4; ++hd) {
    atomicAdd(&tb[hd * 128 + lane], al[hd] * h0);
    atomicAdd(&tb[hd * 128 + 64 + lane], al[hd] * h1);
  }
}

// out = mask( prelu( (t @ B' + bias_sum) / H ) ),  B'[c,d] = W_w[c%128, (c/128)*128 + d]
__global__ __launch_bounds__(256) void node_final_kernel(
    const float* __restrict__ t, const float* __restrict__ W_w, const float* __restrict__ b_w,
    const float* __restrict__ denom, const float* __restrict__ h,
    const float* __restrict__ prelu_a, float* __restrict__ out, int N)
{
  __shared__ float As[128 * 33];
  __shared__ float Bs[32 * 128];
  int tid = threadIdx.x;
  int n0 = blockIdx.x * 128;
  int ty = tid >> 4, tx = tid & 15;
  float acc[8][8];
#pragma unroll
  for (int i = 0; i < 8; ++i)
#pragma unroll
    for (int j = 0; j < 8; ++j) acc[i][j] = 0.f;

  for (int kc = 0; kc < 512; kc += 32) {
    {
      int r = tid >> 1;
      int c0 = (tid & 1) * 16;
      long long row = n0 + r;
#pragma unroll
      for (int i = 0; i < 4; ++i) {
        float4 v = make_float4(0.f, 0.f, 0.f, 0.f);
        if (row < N) v = *reinterpret_cast<const float4*>(&t[row * 512 + kc + c0 + i * 4]);
        float* p = &As[r * 33 + c0 + i * 4];
        p[0] = v.x; p[1] = v.y; p[2] = v.z; p[3] = v.w;
      }
    }
    {
      int r = tid >> 3;
      int c0 = (tid & 7) * 16;
      int cp = kc + r;
      const float* wrow = &W_w[(long long)(cp & 127) * 512 + (cp >> 7) * 128];
#pragma unroll
      for (int i = 0; i < 4; ++i) {
        float4 v = *reinterpret_cast<const float4*>(&wrow[c0 + i * 4]);
        *reinterpret_cast<float4*>(&Bs[r * 128 + c0 + i * 4]) = v;
      }
    }
    __syncthreads();
#pragma unroll
    for (int k = 0; k < 32; ++k) {
      float a[8], b[8];
#pragma unroll
      for (int i = 0; i < 8; ++i) a[i] = As[(ty * 8 + i) * 33 + k];
#pragma unroll
      for (int j = 0; j < 8; j += 4) {
        float4 v = *reinterpret_cast<const float4*>(&Bs[k * 128 + tx * 8 + j]);
        b[j] = v.x; b[j + 1] = v.y; b[j + 2] = v.z; b[j + 3] = v.w;
      }
#pragma unroll
      for (int i = 0; i < 8; ++i)
#pragma unroll
        for (int j = 0; j < 8; ++j)
          acc[i][j] = fmaf(a[i], b[j], acc[i][j]);
    }
    __syncthreads();
  }

  float pa = prelu_a[0];
  float bsum[8];
#pragma unroll
  for (int j = 0; j < 8; ++j) {
    int col = tx * 8 + j;
    bsum[j] = b_w[col] + b_w[128 + col] + b_w[256 + col] + b_w[384 + col];
  }
#pragma unroll
  for (int i = 0; i < 8; ++i) {
    long long row = n0 + ty * 8 + i;
    if (row >= N) continue;
    bool has = denom[row * 4] > 0.f;
#pragma unroll
    for (int j2 = 0; j2 < 2; ++j2) {
      float4 o;
      float* op = &o.x;
#pragma unroll
      for (int q = 0; q < 4; ++q) {
        int j = j2 * 4 + q;
        float v = (acc[i][j] + bsum[j]) * 0.25f;
        op[q] = (v >= 0.f) ? v : pa * v;
      }
      int col = tx * 8 + j2 * 4;
      if (!has) o = *reinterpret_cast<const float4*>(&h[row * 128 + col]);
      *reinterpret_cast<float4*>(&out[row * 128 + col]) = o;
    }
  }
}

extern "C" void kernel_launch(void* const* d_in, const int* in_sizes, int n_in,
                              void* d_out, int out_size, void* d_ws, size_t ws_size,
                              hipStream_t stream)
{
  const float* h         = (const float*)d_in[0];
  const float* edge_feat = (const float*)d_in[1];
  const int*   src       = (const int*)d_in[2];
  const int*   dst       = (const int*)d_in[3];
  const float* W_rel     = (const float*)d_in[4];
  const float* b_rel     = (const float*)d_in[5];
  const float* ln_g      = (const float*)d_in[6];
  const float* ln_b      = (const float*)d_in[7];
  const float* W_att     = (const float*)d_in[8];
  const float* b_att     = (const float*)d_in[9];
  const float* W_w       = (const float*)d_in[10];
  const float* b_w       = (const float*)d_in[11];
  const float* prelu_a   = (const float*)d_in[12];

  int N = in_sizes[0] / D_DIM;
  int E = in_sizes[2];

  char* ws = (char*)d_ws;
  size_t off = 0;
  float* t_buf = (float*)(ws + off); off += (size_t)N * 512 * 4;
  float* u_buf = (float*)(ws + off); off += (size_t)E * 4 * 4;
  float* a12   = (float*)(ws + off); off += (size_t)N * 8 * 4;
  float* m_buf = (float*)(ws + off); off += (size_t)N * 4 * 4;
  float* denom = (float*)(ws + off); off += (size_t)N * 4 * 4;

  hipMemsetAsync(t_buf, 0, (size_t)N * 512 * 4, stream);
  int n4 = N * 4;
  init_md_kernel<<<(n4 + 255) / 256, 256, 0, stream>>>(m_buf, denom, n4);
  node_att_kernel<<<(N * 64 + 255) / 256, 256, 0, stream>>>(h, W_att, a12, N);
  edge_pass1_kernel<<<(E + 127) / 128, 128, 0, stream>>>(edge_feat, src, dst, W_rel, b_rel,
                                                         ln_g, ln_b, W_att, b_att, a12,
                                                         u_buf, m_buf, E);
  edge_pass2_kernel<<<(E + 255) / 256, 256, 0, stream>>>(dst, u_buf, m_buf, denom, E);
  edge_pass3_kernel<<<(int)(((long long)E * 64 + 255) / 256), 256, 0, stream>>>(h, src, dst, u_buf,
                                                                                denom, t_buf, E);
  node_final_kernel<<<(N + 127) / 128, 256, 0, stream>>>(t_buf, W_w, b_w, denom, h, prelu_a,
                                                         (float*)d_out, N);
}

// Round 2
// 324.844 us; speedup vs baseline: 1.8212x; 1.8212x over previous
//
#include <hip/hip_runtime.h>

#define D_DIM 128
#define DE_DIM 64
#define H_NUM 4
#define LN_EPS 1e-5f
#define LEAKY 0.2f

// ---------- CSR build: histogram -> scan -> scatter ----------

__global__ void hist_kernel(const int* __restrict__ dst, int* __restrict__ cnt, int E) {
  int e = blockIdx.x * blockDim.x + threadIdx.x;
  if (e < E) atomicAdd(&cnt[dst[e]], 1);
}

__global__ __launch_bounds__(256) void scan_kernel(
    const int* __restrict__ cnt, int* __restrict__ row_ptr, int* __restrict__ cursor, int N)
{
  __shared__ int offs[257];
  __shared__ int sums[256];
  int tid = threadIdx.x;
  int C = (N + 255) / 256;
  int lo = tid * C;
  int hi = lo + C; if (hi > N) hi = N;
  int s = 0;
  for (int i = lo; i < hi; ++i) s += cnt[i];
  sums[tid] = s;
  __syncthreads();
  if (tid == 0) {
    int acc = 0;
    for (int i = 0; i < 256; ++i) { offs[i] = acc; acc += sums[i]; }
    offs[256] = acc;
  }
  __syncthreads();
  int acc = offs[tid];
  for (int i = lo; i < hi; ++i) {
    row_ptr[i] = acc; cursor[i] = acc; acc += cnt[i];
  }
  if (tid == 255) row_ptr[N] = offs[256];
}

// pos[e] = slot in dst-sorted order; src_sorted[slot] = src[e]
__global__ void scatter_kernel(const int* __restrict__ src, const int* __restrict__ dst,
                               int* __restrict__ cursor, int* __restrict__ pos,
                               int* __restrict__ src_sorted, int E) {
  int e = blockIdx.x * blockDim.x + threadIdx.x;
  if (e < E) {
    int p = atomicAdd(&cursor[dst[e]], 1);
    pos[e] = p;
    src_sorted[p] = src[e];
  }
}

// ---------- node attention partials ----------
// a1[n,hd] = h[n] . W_att[0:128, hd]  ; a2[n,hd] = h[n] . W_att[128:256, hd]
__global__ __launch_bounds__(256) void node_att_kernel(
    const float* __restrict__ h, const float* __restrict__ W_att,
    float* __restrict__ a12, int N)
{
  int lane = threadIdx.x & 63;
  int wid = (int)((blockIdx.x * (long long)blockDim.x + threadIdx.x) >> 6);
  if (wid >= N) return;
  const float* hr = &h[(long long)wid * D_DIM];
  float h0 = hr[lane], h1 = hr[64 + lane];
  float p[8];
#pragma unroll
  for (int hd = 0; hd < 4; ++hd) {
    p[hd]     = h0 * W_att[lane * 4 + hd]         + h1 * W_att[(64 + lane) * 4 + hd];
    p[4 + hd] = h0 * W_att[(128 + lane) * 4 + hd] + h1 * W_att[(192 + lane) * 4 + hd];
  }
#pragma unroll
  for (int j = 0; j < 8; ++j) {
    float v = p[j];
#pragma unroll
    for (int off = 32; off; off >>= 1) v += __shfl_xor(v, off);
    if (lane == 0) a12[(long long)wid * 8 + j] = v;
  }
}

// ---------- fused edge pass: ef@W_rel + LN + ReLU + .Wa3 + leaky -> u_sorted ----------
__global__ __launch_bounds__(128) void edge_pass1_kernel(
    const float* __restrict__ edge_feat, const int* __restrict__ src, const int* __restrict__ dst,
    const float* __restrict__ W_rel, const float* __restrict__ b_rel,
    const float* __restrict__ ln_g, const float* __restrict__ ln_b,
    const float* __restrict__ W_att, const float* __restrict__ b_att,
    const float* __restrict__ a12, const int* __restrict__ pos,
    float* __restrict__ u_sorted, int E)
{
  __shared__ float ef_lds[2][64 * 65];   // +1 pad: conflict-free row reads
  int wv = threadIdx.x >> 6;
  int lane = threadIdx.x & 63;
  long long e0 = ((long long)blockIdx.x * 2 + wv) * 64;
  float* lds = ef_lds[wv];

  {
    int rb = lane >> 4;            // 0..3
    int c4 = (lane & 15) * 4;
#pragma unroll
    for (int it = 0; it < 16; ++it) {
      int r = it * 4 + rb;
      long long e = e0 + r;
      float4 v = make_float4(0.f, 0.f, 0.f, 0.f);
      if (e < E) v = *reinterpret_cast<const float4*>(&edge_feat[e * DE_DIM + c4]);
      float* p = &lds[r * 65 + c4];
      p[0] = v.x; p[1] = v.y; p[2] = v.z; p[3] = v.w;
    }
  }
  __syncthreads();

  long long e = e0 + lane;
  float x[D_DIM];
#pragma unroll
  for (int d = 0; d < D_DIM; ++d) x[d] = b_rel[d];
  for (int k = 0; k < DE_DIM; ++k) {
    float s = lds[lane * 65 + k];
    const float* w = &W_rel[k * D_DIM];   // wave-uniform -> s_load
#pragma unroll
    for (int d = 0; d < D_DIM; ++d) x[d] = fmaf(s, w[d], x[d]);
  }
  float sum = 0.f;
#pragma unroll
  for (int d = 0; d < D_DIM; ++d) sum += x[d];
  float mu = sum * (1.f / D_DIM);
  float sq = 0.f;
#pragma unroll
  for (int d = 0; d < D_DIM; ++d) { float c = x[d] - mu; sq += c * c; }
  float rstd = rsqrtf(sq * (1.f / D_DIM) + LN_EPS);
  float u[4] = {0.f, 0.f, 0.f, 0.f};
#pragma unroll
  for (int d = 0; d < D_DIM; ++d) {
    float wef = (x[d] - mu) * rstd * ln_g[d] + ln_b[d];
    wef = fmaxf(wef, 0.f);
#pragma unroll
    for (int hd = 0; hd < 4; ++hd) u[hd] = fmaf(wef, W_att[(256 + d) * 4 + hd], u[hd]);
  }
  if (e < E) {
    int sN = src[e], dN = dst[e];
    const float* ad = &a12[(long long)dN * 8];
    const float* as = &a12[(long long)sN * 8 + 4];
    float4 uo;
    float* up = &uo.x;
#pragma unroll
    for (int hd = 0; hd < 4; ++hd) {
      float v = ad[hd] + as[hd] + u[hd] + b_att[hd];
      up[hd] = (v >= 0.f) ? v : LEAKY * v;
    }
    *reinterpret_cast<float4*>(&u_sorted[(long long)pos[e] * 4]) = uo;
  }
}

// ---------- per-node segment softmax + gather aggregate (wave per node) ----------
// t[n, hd*128+d] = sum_e alpha[e,hd] * h[src[e], d]
__global__ __launch_bounds__(256) void node_agg_kernel(
    const float* __restrict__ h, const int* __restrict__ src_sorted,
    const float* __restrict__ u_sorted, const int* __restrict__ row_ptr,
    float* __restrict__ t, int N)
{
  int lane = threadIdx.x & 63;
  int n = (int)((blockIdx.x * (long long)blockDim.x + threadIdx.x) >> 6);
  if (n >= N) return;
  int lo = row_ptr[n], hi = row_ptr[n + 1];
  float* tb = &t[(long long)n * 512];
  if (lo == hi) {
#pragma unroll
    for (int hd = 0; hd < 4; ++hd) {
      tb[hd * 128 + lane] = 0.f;
      tb[hd * 128 + 64 + lane] = 0.f;
    }
    return;
  }
  float m0 = -1e30f, m1 = -1e30f, m2 = -1e30f, m3 = -1e30f;
  for (int p = lo; p < hi; ++p) {
    float4 u = *reinterpret_cast<const float4*>(&u_sorted[(long long)p * 4]);
    m0 = fmaxf(m0, u.x); m1 = fmaxf(m1, u.y);
    m2 = fmaxf(m2, u.z); m3 = fmaxf(m3, u.w);
  }
  float d0 = 0.f, d1 = 0.f, d2 = 0.f, d3 = 0.f;
  float acc[8];
#pragma unroll
  for (int i = 0; i < 8; ++i) acc[i] = 0.f;
  for (int p = lo; p < hi; ++p) {
    float4 u = *reinterpret_cast<const float4*>(&u_sorted[(long long)p * 4]);
    float p0 = __expf(u.x - m0), p1 = __expf(u.y - m1);
    float p2 = __expf(u.z - m2), p3 = __expf(u.w - m3);
    d0 += p0; d1 += p1; d2 += p2; d3 += p3;
    const float* hs = &h[(long long)src_sorted[p] * D_DIM];
    float h0 = hs[lane], h1 = hs[64 + lane];
    acc[0] = fmaf(p0, h0, acc[0]); acc[1] = fmaf(p0, h1, acc[1]);
    acc[2] = fmaf(p1, h0, acc[2]); acc[3] = fmaf(p1, h1, acc[3]);
    acc[4] = fmaf(p2, h0, acc[4]); acc[5] = fmaf(p2, h1, acc[5]);
    acc[6] = fmaf(p3, h0, acc[6]); acc[7] = fmaf(p3, h1, acc[7]);
  }
  float r0 = 1.f / d0, r1 = 1.f / d1, r2 = 1.f / d2, r3 = 1.f / d3;
  tb[0 * 128 + lane] = acc[0] * r0; tb[0 * 128 + 64 + lane] = acc[1] * r0;
  tb[1 * 128 + lane] = acc[2] * r1; tb[1 * 128 + 64 + lane] = acc[3] * r1;
  tb[2 * 128 + lane] = acc[4] * r2; tb[2 * 128 + 64 + lane] = acc[5] * r2;
  tb[3 * 128 + lane] = acc[6] * r3; tb[3 * 128 + 64 + lane] = acc[7] * r3;
}

// ---------- final node GEMM: out = mask(prelu((t @ B' + bias_sum)/H)) ----------
// B'[c,d] = W_w[c%128, (c/128)*128 + d]
__global__ __launch_bounds__(256) void node_final_kernel(
    const float* __restrict__ t, const float* __restrict__ W_w, const float* __restrict__ b_w,
    const int* __restrict__ row_ptr, const float* __restrict__ h,
    const float* __restrict__ prelu_a, float* __restrict__ out, int N)
{
  __shared__ float As[128 * 33];
  __shared__ float Bs[32 * 128];
  int tid = threadIdx.x;
  int n0 = blockIdx.x * 128;
  int ty = tid >> 4, tx = tid & 15;
  float acc[8][8];
#pragma unroll
  for (int i = 0; i < 8; ++i)
#pragma unroll
    for (int j = 0; j < 8; ++j) acc[i][j] = 0.f;

  for (int kc = 0; kc < 512; kc += 32) {
    {
      int r = tid >> 1;
      int c0 = (tid & 1) * 16;
      long long row = n0 + r;
#pragma unroll
      for (int i = 0; i < 4; ++i) {
        float4 v = make_float4(0.f, 0.f, 0.f, 0.f);
        if (row < N) v = *reinterpret_cast<const float4*>(&t[row * 512 + kc + c0 + i * 4]);
        float* p = &As[r * 33 + c0 + i * 4];
        p[0] = v.x; p[1] = v.y; p[2] = v.z; p[3] = v.w;
      }
    }
    {
      int r = tid >> 3;
      int c0 = (tid & 7) * 16;
      int cp = kc + r;
      const float* wrow = &W_w[(long long)(cp & 127) * 512 + (cp >> 7) * 128];
#pragma unroll
      for (int i = 0; i < 4; ++i) {
        float4 v = *reinterpret_cast<const float4*>(&wrow[c0 + i * 4]);
        *reinterpret_cast<float4*>(&Bs[r * 128 + c0 + i * 4]) = v;
      }
    }
    __syncthreads();
#pragma unroll
    for (int k = 0; k < 32; ++k) {
      float a[8], b[8];
#pragma unroll
      for (int i = 0; i < 8; ++i) a[i] = As[(ty * 8 + i) * 33 + k];
#pragma unroll
      for (int j = 0; j < 8; j += 4) {
        float4 v = *reinterpret_cast<const float4*>(&Bs[k * 128 + tx * 8 + j]);
        b[j] = v.x; b[j + 1] = v.y; b[j + 2] = v.z; b[j + 3] = v.w;
      }
#pragma unroll
      for (int i = 0; i < 8; ++i)
#pragma unroll
        for (int j = 0; j < 8; ++j)
          acc[i][j] = fmaf(a[i], b[j], acc[i][j]);
    }
    __syncthreads();
  }

  float pa = prelu_a[0];
  float bsum[8];
#pragma unroll
  for (int j = 0; j < 8; ++j) {
    int col = tx * 8 + j;
    bsum[j] = b_w[col] + b_w[128 + col] + b_w[256 + col] + b_w[384 + col];
  }
#pragma unroll
  for (int i = 0; i < 8; ++i) {
    long long row = n0 + ty * 8 + i;
    if (row >= N) continue;
    bool has = row_ptr[row + 1] > row_ptr[row];
#pragma unroll
    for (int j2 = 0; j2 < 2; ++j2) {
      float4 o;
      float* op = &o.x;
#pragma unroll
      for (int q = 0; q < 4; ++q) {
        int j = j2 * 4 + q;
        float v = (acc[i][j] + bsum[j]) * 0.25f;
        op[q] = (v >= 0.f) ? v : pa * v;
      }
      int col = tx * 8 + j2 * 4;
      if (!has) o = *reinterpret_cast<const float4*>(&h[row * 128 + col]);
      *reinterpret_cast<float4*>(&out[row * 128 + col]) = o;
    }
  }
}

extern "C" void kernel_launch(void* const* d_in, const int* in_sizes, int n_in,
                              void* d_out, int out_size, void* d_ws, size_t ws_size,
                              hipStream_t stream)
{
  const float* h         = (const float*)d_in[0];
  const float* edge_feat = (const float*)d_in[1];
  const int*   src       = (const int*)d_in[2];
  const int*   dst       = (const int*)d_in[3];
  const float* W_rel     = (const float*)d_in[4];
  const float* b_rel     = (const float*)d_in[5];
  const float* ln_g      = (const float*)d_in[6];
  const float* ln_b      = (const float*)d_in[7];
  const float* W_att     = (const float*)d_in[8];
  const float* b_att     = (const float*)d_in[9];
  const float* W_w       = (const float*)d_in[10];
  const float* b_w       = (const float*)d_in[11];
  const float* prelu_a   = (const float*)d_in[12];

  int N = in_sizes[0] / D_DIM;
  int E = in_sizes[2];

  char* ws = (char*)d_ws;
  size_t off = 0;
  float* t_buf      = (float*)(ws + off); off += (size_t)N * 512 * 4;
  float* u_sorted   = (float*)(ws + off); off += (size_t)E * 4 * 4;
  float* a12        = (float*)(ws + off); off += (size_t)N * 8 * 4;
  int*   row_ptr    = (int*)(ws + off);   off += (size_t)(N + 1) * 4;
  int*   cnt        = (int*)(ws + off);   off += (size_t)N * 4;
  int*   cursor     = (int*)(ws + off);   off += (size_t)N * 4;
  int*   pos        = (int*)(ws + off);   off += (size_t)E * 4;
  int*   src_sorted = (int*)(ws + off);   off += (size_t)E * 4;

  hipMemsetAsync(cnt, 0, (size_t)N * 4, stream);
  hist_kernel<<<(E + 255) / 256, 256, 0, stream>>>(dst, cnt, E);
  scan_kernel<<<1, 256, 0, stream>>>(cnt, row_ptr, cursor, N);
  scatter_kernel<<<(E + 255) / 256, 256, 0, stream>>>(src, dst, cursor, pos, src_sorted, E);
  node_att_kernel<<<(N * 64 + 255) / 256, 256, 0, stream>>>(h, W_att, a12, N);
  edge_pass1_kernel<<<(E + 127) / 128, 128, 0, stream>>>(edge_feat, src, dst, W_rel, b_rel,
                                                         ln_g, ln_b, W_att, b_att, a12, pos,
                                                         u_sorted, E);
  node_agg_kernel<<<(int)(((long long)N * 64 + 255) / 256), 256, 0, stream>>>(
      h, src_sorted, u_sorted, row_ptr, t_buf, N);
  node_final_kernel<<<(N + 127) / 128, 256, 0, stream>>>(t_buf, W_w, b_w, row_ptr, h, prelu_a,
                                                         (float*)d_out, N);
}

// Round 3
// 235.982 us; speedup vs baseline: 2.5070x; 1.3766x over previous
//
#include <hip/hip_runtime.h>

#define D_DIM 128
#define DE_DIM 64
#define LN_EPS 1e-5f
#define LEAKY 0.2f

typedef __attribute__((ext_vector_type(4))) float f32x4;
typedef __attribute__((ext_vector_type(8))) short s16x8;

static __device__ __forceinline__ unsigned short f2bf(float f) {
  unsigned int u = __float_as_uint(f);
  unsigned int r = (u + 0x7fffu + ((u >> 16) & 1u)) >> 16;
  return (unsigned short)r;
}

// ---------- CSR build: histogram -> scan -> scatter ----------

__global__ void hist_kernel(const int* __restrict__ dst, int* __restrict__ cnt, int E) {
  int e = blockIdx.x * blockDim.x + threadIdx.x;
  if (e < E) atomicAdd(&cnt[dst[e]], 1);
}

__global__ __launch_bounds__(256) void scan_kernel(
    const int* __restrict__ cnt, int* __restrict__ row_ptr, int* __restrict__ cursor, int N)
{
  __shared__ int offs[257];
  __shared__ int sums[256];
  int tid = threadIdx.x;
  int C = (N + 255) / 256;
  int lo = tid * C;
  int hi = lo + C; if (hi > N) hi = N;
  int s = 0;
  for (int i = lo; i < hi; ++i) s += cnt[i];
  sums[tid] = s;
  __syncthreads();
  if (tid == 0) {
    int acc = 0;
    for (int i = 0; i < 256; ++i) { offs[i] = acc; acc += sums[i]; }
    offs[256] = acc;
  }
  __syncthreads();
  int acc = offs[tid];
  for (int i = lo; i < hi; ++i) {
    row_ptr[i] = acc; cursor[i] = acc; acc += cnt[i];
  }
  if (tid == 255) row_ptr[N] = offs[256];
}

__global__ void scatter_kernel(const int* __restrict__ src, const int* __restrict__ dst,
                               int* __restrict__ cursor, int* __restrict__ pos,
                               int* __restrict__ src_sorted, int E) {
  int e = blockIdx.x * blockDim.x + threadIdx.x;
  if (e < E) {
    int p = atomicAdd(&cursor[dst[e]], 1);
    pos[e] = p;
    src_sorted[p] = src[e];
  }
}

// ---------- weight pre-pack kernels (tiny, one-shot) ----------
// wrel_pk[dg][ks][lane][j] = bf16(W_rel[ks*32 + 8*(lane>>4)+j][16*dg + (lane&15)])
__global__ void prep_wrel_kernel(const float* __restrict__ W_rel, unsigned short* __restrict__ wrel_pk) {
  int tid = blockIdx.x * blockDim.x + threadIdx.x;   // 8192 total
  if (tid >= 8192) return;
  int j = tid & 7, lane = (tid >> 3) & 63, ks = (tid >> 9) & 1, dg = tid >> 10;
  int k = ks * 32 + 8 * (lane >> 4) + j;
  int col = 16 * dg + (lane & 15);
  wrel_pk[tid] = f2bf(W_rel[k * D_DIM + col]);
}

// B'[c][d] = W_w[c&127][(c>>7)*128 + d]; ww_pk[kc][dg][lane][j] = bf16(B'[kc*32+8*(lane>>4)+j][16*dg+(lane&15)])
__global__ void prep_ww_kernel(const float* __restrict__ W_w, unsigned short* __restrict__ ww_pk) {
  int tid = blockIdx.x * blockDim.x + threadIdx.x;   // 65536 total
  if (tid >= 65536) return;
  int j = tid & 7, lane = (tid >> 3) & 63, dg = (tid >> 9) & 7, kc = tid >> 12;
  int c = kc * 32 + 8 * (lane >> 4) + j;
  int d = 16 * dg + (lane & 15);
  ww_pk[tid] = f2bf(W_w[(long long)(c & 127) * 512 + (c >> 7) * 128 + d]);
}

// ---------- node attention partials ----------
__global__ __launch_bounds__(256) void node_att_kernel(
    const float* __restrict__ h, const float* __restrict__ W_att,
    float* __restrict__ a12, int N)
{
  int lane = threadIdx.x & 63;
  int wid = (int)((blockIdx.x * (long long)blockDim.x + threadIdx.x) >> 6);
  if (wid >= N) return;
  const float* hr = &h[(long long)wid * D_DIM];
  float h0 = hr[lane], h1 = hr[64 + lane];
  float p[8];
#pragma unroll
  for (int hd = 0; hd < 4; ++hd) {
    p[hd]     = h0 * W_att[lane * 4 + hd]         + h1 * W_att[(64 + lane) * 4 + hd];
    p[4 + hd] = h0 * W_att[(128 + lane) * 4 + hd] + h1 * W_att[(192 + lane) * 4 + hd];
  }
#pragma unroll
  for (int j = 0; j < 8; ++j) {
    float v = p[j];
#pragma unroll
    for (int off = 32; off; off >>= 1) v += __shfl_xor(v, off);
    if (lane == 0) a12[(long long)wid * 8 + j] = v;
  }
}

// ---------- fused edge pass, MFMA version ----------
// Per wave: 16 edges. x = ef@W_rel (+b_rel) via mfma; LN; ReLU; u = .Wa3; leaky; store u_sorted[pos].
__global__ __launch_bounds__(256) void edge_mfma_kernel(
    const float* __restrict__ edge_feat, const int* __restrict__ src, const int* __restrict__ dst,
    const unsigned short* __restrict__ wrel_pk, const float* __restrict__ b_rel,
    const float* __restrict__ ln_g, const float* __restrict__ ln_b,
    const float* __restrict__ W_att, const float* __restrict__ b_att,
    const float* __restrict__ a12, const int* __restrict__ pos,
    float* __restrict__ u_sorted, int E)
{
  int l = threadIdx.x & 63;
  int wv = threadIdx.x >> 6;
  long long e0 = (long long)blockIdx.x * 64 + wv * 16;

  // preload B fragments (W_rel), 64 VGPRs
  s16x8 Bf[8][2];
#pragma unroll
  for (int dg = 0; dg < 8; ++dg)
#pragma unroll
    for (int ks = 0; ks < 2; ++ks)
      Bf[dg][ks] = *reinterpret_cast<const s16x8*>(&wrel_pk[((dg * 2 + ks) * 64 + l) * 8]);

  f32x4 zero4 = {0.f, 0.f, 0.f, 0.f};
  f32x4 acc[8];
#pragma unroll
  for (int dg = 0; dg < 8; ++dg) acc[dg] = zero4;

  long long er = e0 + (l & 15);
  const float* ef = &edge_feat[er * DE_DIM + 8 * (l >> 4)];
  bool erok = (er < E);
#pragma unroll
  for (int ks = 0; ks < 2; ++ks) {
    s16x8 a;
    if (erok) {
      float4 v0 = *reinterpret_cast<const float4*>(&ef[ks * 32]);
      float4 v1 = *reinterpret_cast<const float4*>(&ef[ks * 32 + 4]);
      a[0] = (short)f2bf(v0.x); a[1] = (short)f2bf(v0.y);
      a[2] = (short)f2bf(v0.z); a[3] = (short)f2bf(v0.w);
      a[4] = (short)f2bf(v1.x); a[5] = (short)f2bf(v1.y);
      a[6] = (short)f2bf(v1.z); a[7] = (short)f2bf(v1.w);
    } else {
#pragma unroll
      for (int j = 0; j < 8; ++j) a[j] = 0;
    }
#pragma unroll
    for (int dg = 0; dg < 8; ++dg)
      acc[dg] = __builtin_amdgcn_mfma_f32_16x16x32_bf16(a, Bf[dg][ks], acc[dg], 0, 0, 0);
  }

  // add b_rel and LN stats. lane holds rows 4*(l>>4)+i, cols 16*dg+(l&15)
  int cq = l & 15;
#pragma unroll
  for (int dg = 0; dg < 8; ++dg) {
    float br = b_rel[16 * dg + cq];
#pragma unroll
    for (int i = 0; i < 4; ++i) acc[dg][i] += br;
  }
  float mu[4], rstd[4];
#pragma unroll
  for (int i = 0; i < 4; ++i) {
    float s = 0.f, q = 0.f;
#pragma unroll
    for (int dg = 0; dg < 8; ++dg) { float v = acc[dg][i]; s += v; q += v * v; }
#pragma unroll
    for (int off = 1; off < 16; off <<= 1) { s += __shfl_xor(s, off); q += __shfl_xor(q, off); }
    float m = s * (1.f / 128.f);
    float var = q * (1.f / 128.f) - m * m;
    mu[i] = m;
    rstd[i] = rsqrtf(var + LN_EPS);
  }

  // wef = relu(LN(x)); u[i][hd] = sum_col wef * Wa3[col][hd]
  float u[4][4];
#pragma unroll
  for (int i = 0; i < 4; ++i)
#pragma unroll
    for (int hd = 0; hd < 4; ++hd) u[i][hd] = 0.f;
#pragma unroll
  for (int dg = 0; dg < 8; ++dg) {
    int col = 16 * dg + cq;
    float g = ln_g[col], bb = ln_b[col];
    float4 wa = *reinterpret_cast<const float4*>(&W_att[(256 + col) * 4]);
#pragma unroll
    for (int i = 0; i < 4; ++i) {
      float w = (acc[dg][i] - mu[i]) * rstd[i] * g + bb;
      w = fmaxf(w, 0.f);
      u[i][0] = fmaf(w, wa.x, u[i][0]);
      u[i][1] = fmaf(w, wa.y, u[i][1]);
      u[i][2] = fmaf(w, wa.z, u[i][2]);
      u[i][3] = fmaf(w, wa.w, u[i][3]);
    }
  }
#pragma unroll
  for (int i = 0; i < 4; ++i)
#pragma unroll
    for (int hd = 0; hd < 4; ++hd) {
      float v = u[i][hd];
#pragma unroll
      for (int off = 1; off < 16; off <<= 1) v += __shfl_xor(v, off);
      u[i][hd] = v;
    }

  if (cq < 4) {          // cq = head index
    float ba = b_att[cq];
#pragma unroll
    for (int i = 0; i < 4; ++i) {
      long long e = e0 + 4 * (l >> 4) + i;
      if (e < E) {
        int sN = src[e], dN = dst[e];
        float v = a12[(long long)dN * 8 + cq] + a12[(long long)sN * 8 + 4 + cq] + u[i][cq] + ba;
        v = (v >= 0.f) ? v : LEAKY * v;
        u_sorted[(long long)pos[e] * 4 + cq] = v;
      }
    }
  }
}

// ---------- per-node segment softmax + gather aggregate (wave per node), t in bf16 ----------
__global__ __launch_bounds__(256) void node_agg_kernel(
    const float* __restrict__ h, const int* __restrict__ src_sorted,
    const float* __restrict__ u_sorted, const int* __restrict__ row_ptr,
    unsigned short* __restrict__ t, int N)
{
  int lane = threadIdx.x & 63;
  int n = (int)((blockIdx.x * (long long)blockDim.x + threadIdx.x) >> 6);
  if (n >= N) return;
  int lo = row_ptr[n], hi = row_ptr[n + 1];
  unsigned short* tb = &t[(long long)n * 512];
  if (lo == hi) {
#pragma unroll
    for (int hd = 0; hd < 4; ++hd) {
      tb[hd * 128 + lane] = 0;
      tb[hd * 128 + 64 + lane] = 0;
    }
    return;
  }
  float m0 = -1e30f, m1 = -1e30f, m2 = -1e30f, m3 = -1e30f;
  for (int p = lo; p < hi; ++p) {
    float4 u = *reinterpret_cast<const float4*>(&u_sorted[(long long)p * 4]);
    m0 = fmaxf(m0, u.x); m1 = fmaxf(m1, u.y);
    m2 = fmaxf(m2, u.z); m3 = fmaxf(m3, u.w);
  }
  float d0 = 0.f, d1 = 0.f, d2 = 0.f, d3 = 0.f;
  float acc[8];
#pragma unroll
  for (int i = 0; i < 8; ++i) acc[i] = 0.f;
  for (int p = lo; p < hi; ++p) {
    float4 u = *reinterpret_cast<const float4*>(&u_sorted[(long long)p * 4]);
    float p0 = __expf(u.x - m0), p1 = __expf(u.y - m1);
    float p2 = __expf(u.z - m2), p3 = __expf(u.w - m3);
    d0 += p0; d1 += p1; d2 += p2; d3 += p3;
    const float* hs = &h[(long long)src_sorted[p] * D_DIM];
    float h0 = hs[lane], h1 = hs[64 + lane];
    acc[0] = fmaf(p0, h0, acc[0]); acc[1] = fmaf(p0, h1, acc[1]);
    acc[2] = fmaf(p1, h0, acc[2]); acc[3] = fmaf(p1, h1, acc[3]);
    acc[4] = fmaf(p2, h0, acc[4]); acc[5] = fmaf(p2, h1, acc[5]);
    acc[6] = fmaf(p3, h0, acc[6]); acc[7] = fmaf(p3, h1, acc[7]);
  }
  float r0 = 1.f / d0, r1 = 1.f / d1, r2 = 1.f / d2, r3 = 1.f / d3;
  tb[0 * 128 + lane] = f2bf(acc[0] * r0); tb[0 * 128 + 64 + lane] = f2bf(acc[1] * r0);
  tb[1 * 128 + lane] = f2bf(acc[2] * r1); tb[1 * 128 + 64 + lane] = f2bf(acc[3] * r1);
  tb[2 * 128 + lane] = f2bf(acc[4] * r2); tb[2 * 128 + 64 + lane] = f2bf(acc[5] * r2);
  tb[3 * 128 + lane] = f2bf(acc[6] * r3); tb[3 * 128 + 64 + lane] = f2bf(acc[7] * r3);
}

// ---------- final node GEMM via MFMA: out = mask(prelu((t @ B' + bias_sum)/H)) ----------
__global__ __launch_bounds__(256) void node_final_mfma(
    const unsigned short* __restrict__ t_bf, const unsigned short* __restrict__ ww_pk,
    const float* __restrict__ b_w, const int* __restrict__ row_ptr,
    const float* __restrict__ h, const float* __restrict__ prelu_a,
    float* __restrict__ out, int N)
{
  int l = threadIdx.x & 63;
  int wv = threadIdx.x >> 6;
  int base = blockIdx.x * 128 + wv * 32;

  f32x4 zero4 = {0.f, 0.f, 0.f, 0.f};
  f32x4 acc[2][8];
#pragma unroll
  for (int rg = 0; rg < 2; ++rg)
#pragma unroll
    for (int dg = 0; dg < 8; ++dg) acc[rg][dg] = zero4;

  s16x8 azero;
#pragma unroll
  for (int j = 0; j < 8; ++j) azero[j] = 0;

  for (int kc = 0; kc < 16; ++kc) {
    s16x8 a[2];
#pragma unroll
    for (int rg = 0; rg < 2; ++rg) {
      int row = base + rg * 16 + (l & 15);
      a[rg] = (row < N)
        ? *reinterpret_cast<const s16x8*>(&t_bf[(long long)row * 512 + kc * 32 + 8 * (l >> 4)])
        : azero;
    }
#pragma unroll
    for (int dg = 0; dg < 8; ++dg) {
      s16x8 b = *reinterpret_cast<const s16x8*>(&ww_pk[((long long)(kc * 8 + dg) * 64 + l) * 8]);
      acc[0][dg] = __builtin_amdgcn_mfma_f32_16x16x32_bf16(a[0], b, acc[0][dg], 0, 0, 0);
      acc[1][dg] = __builtin_amdgcn_mfma_f32_16x16x32_bf16(a[1], b, acc[1][dg], 0, 0, 0);
    }
  }

  float pa = prelu_a[0];
  int cq = l & 15;
  float bs[8];
#pragma unroll
  for (int dg = 0; dg < 8; ++dg) {
    int col = 16 * dg + cq;
    bs[dg] = b_w[col] + b_w[128 + col] + b_w[256 + col] + b_w[384 + col];
  }
#pragma unroll
  for (int rg = 0; rg < 2; ++rg)
#pragma unroll
    for (int i = 0; i < 4; ++i) {
      int row = base + rg * 16 + 4 * (l >> 4) + i;
      if (row >= N) continue;
      bool has = row_ptr[row + 1] > row_ptr[row];
#pragma unroll
      for (int dg = 0; dg < 8; ++dg) {
        int col = 16 * dg + cq;
        float v = (acc[rg][dg][i] + bs[dg]) * 0.25f;
        v = (v >= 0.f) ? v : pa * v;
        if (!has) v = h[(long long)row * 128 + col];
        out[(long long)row * 128 + col] = v;
      }
    }
}

extern "C" void kernel_launch(void* const* d_in, const int* in_sizes, int n_in,
                              void* d_out, int out_size, void* d_ws, size_t ws_size,
                              hipStream_t stream)
{
  const float* h         = (const float*)d_in[0];
  const float* edge_feat = (const float*)d_in[1];
  const int*   src       = (const int*)d_in[2];
  const int*   dst       = (const int*)d_in[3];
  const float* W_rel     = (const float*)d_in[4];
  const float* b_rel     = (const float*)d_in[5];
  const float* ln_g      = (const float*)d_in[6];
  const float* ln_b      = (const float*)d_in[7];
  const float* W_att     = (const float*)d_in[8];
  const float* b_att     = (const float*)d_in[9];
  const float* W_w       = (const float*)d_in[10];
  const float* b_w       = (const float*)d_in[11];
  const float* prelu_a   = (const float*)d_in[12];

  int N = in_sizes[0] / D_DIM;
  int E = in_sizes[2];

  char* ws = (char*)d_ws;
  size_t off = 0;
  unsigned short* t_bf    = (unsigned short*)(ws + off); off += (size_t)N * 512 * 2;
  float* u_sorted         = (float*)(ws + off);          off += (size_t)E * 4 * 4;
  float* a12              = (float*)(ws + off);          off += (size_t)N * 8 * 4;
  int*   row_ptr          = (int*)(ws + off);            off += (size_t)(N + 1) * 4;
  int*   cnt              = (int*)(ws + off);            off += (size_t)N * 4;
  int*   cursor           = (int*)(ws + off);            off += (size_t)N * 4;
  int*   pos              = (int*)(ws + off);            off += (size_t)E * 4;
  int*   src_sorted       = (int*)(ws + off);            off += (size_t)E * 4;
  unsigned short* wrel_pk = (unsigned short*)(ws + off); off += 8192 * 2;
  unsigned short* ww_pk   = (unsigned short*)(ws + off); off += 65536 * 2;

  hipMemsetAsync(cnt, 0, (size_t)N * 4, stream);
  hist_kernel<<<(E + 255) / 256, 256, 0, stream>>>(dst, cnt, E);
  scan_kernel<<<1, 256, 0, stream>>>(cnt, row_ptr, cursor, N);
  scatter_kernel<<<(E + 255) / 256, 256, 0, stream>>>(src, dst, cursor, pos, src_sorted, E);
  prep_wrel_kernel<<<32, 256, 0, stream>>>(W_rel, wrel_pk);
  prep_ww_kernel<<<256, 256, 0, stream>>>(W_w, ww_pk);
  node_att_kernel<<<(N * 64 + 255) / 256, 256, 0, stream>>>(h, W_att, a12, N);
  edge_mfma_kernel<<<(E + 63) / 64, 256, 0, stream>>>(edge_feat, src, dst, wrel_pk, b_rel,
                                                      ln_g, ln_b, W_att, b_att, a12, pos,
                                                      u_sorted, E);
  node_agg_kernel<<<(int)(((long long)N * 64 + 255) / 256), 256, 0, stream>>>(
      h, src_sorted, u_sorted, row_ptr, t_bf, N);
  node_final_mfma<<<(N + 127) / 128, 256, 0, stream>>>(t_bf, ww_pk, b_w, row_ptr, h, prelu_a,
                                                       (float*)d_out, N);
}

// Round 4
// 183.070 us; speedup vs baseline: 3.2316x; 1.2890x over previous
//
#include <hip/hip_runtime.h>

#define D_DIM 128
#define DE_DIM 64
#define LN_EPS 1e-5f
#define LEAKY 0.2f

typedef __attribute__((ext_vector_type(4))) float f32x4;
typedef __attribute__((ext_vector_type(8))) short s16x8;

static __device__ __forceinline__ unsigned short f2bf(float f) {
  unsigned int u = __float_as_uint(f);
  unsigned int r = (u + 0x7fffu + ((u >> 16) & 1u)) >> 16;
  return (unsigned short)r;
}

// ---------- CSR build: histogram -> hierarchical scan -> scatter ----------

__global__ void hist_kernel(const int* __restrict__ dst, int* __restrict__ cnt, int E) {
  int e = blockIdx.x * blockDim.x + threadIdx.x;
  if (e < E) atomicAdd(&cnt[dst[e]], 1);
}

// stage 1: per-block (1024 elems) sums, coalesced int4 loads
__global__ __launch_bounds__(256) void scan1_kernel(
    const int* __restrict__ cnt, int* __restrict__ bsum, int N)
{
  __shared__ int red[256];
  int b = blockIdx.x, tid = threadIdx.x;
  int i0 = b * 1024 + tid * 4;
  int s = 0;
  if (i0 + 3 < N) {
    int4 v = *reinterpret_cast<const int4*>(&cnt[i0]);
    s = v.x + v.y + v.z + v.w;
  } else {
#pragma unroll
    for (int j = 0; j < 4; ++j) if (i0 + j < N) s += cnt[i0 + j];
  }
  red[tid] = s;
  __syncthreads();
  for (int off = 128; off; off >>= 1) {
    if (tid < off) red[tid] += red[tid + off];
    __syncthreads();
  }
  if (tid == 0) bsum[b] = red[0];
}

// stage 2: one wave scans block sums -> exclusive offsets + total
__global__ void scan2_kernel(const int* __restrict__ bsum, int* __restrict__ boff,
                             int* __restrict__ row_ptrN, int nb)
{
  int l = threadIdx.x;   // 64 threads
  int v = (l < nb) ? bsum[l] : 0;
  int inc = v;
#pragma unroll
  for (int off = 1; off < 64; off <<= 1) {
    int t = __shfl_up(inc, off);
    if (l >= off) inc += t;
  }
  if (l < nb) boff[l] = inc - v;
  if (l == 63) *row_ptrN = inc;
}

// stage 3: per-block exclusive scan (wave shfl + per-wave offsets), write row_ptr & cursor
__global__ __launch_bounds__(256) void scan3_kernel(
    const int* __restrict__ cnt, const int* __restrict__ boff,
    int* __restrict__ row_ptr, int* __restrict__ cursor, int N)
{
  __shared__ int wsum[4];
  int b = blockIdx.x, tid = threadIdx.x;
  int lane = tid & 63, wv = tid >> 6;
  int i0 = b * 1024 + tid * 4;
  int c[4];
  int s = 0;
#pragma unroll
  for (int j = 0; j < 4; ++j) {
    int i = i0 + j;
    c[j] = (i < N) ? cnt[i] : 0;
    s += c[j];
  }
  int inc = s;
#pragma unroll
  for (int off = 1; off < 64; off <<= 1) {
    int t = __shfl_up(inc, off);
    if (lane >= off) inc += t;
  }
  if (lane == 63) wsum[wv] = inc;
  __syncthreads();
  int woff = 0;
  for (int w = 0; w < wv; ++w) woff += wsum[w];
  int excl = boff[b] + woff + (inc - s);
#pragma unroll
  for (int j = 0; j < 4; ++j) {
    int i = i0 + j;
    if (i < N) { row_ptr[i] = excl; cursor[i] = excl; excl += c[j]; }
  }
}

__global__ void scatter_kernel(const int* __restrict__ src, const int* __restrict__ dst,
                               int* __restrict__ cursor, int* __restrict__ pos,
                               int* __restrict__ src_sorted, int E) {
  int e = blockIdx.x * blockDim.x + threadIdx.x;
  if (e < E) {
    int p = atomicAdd(&cursor[dst[e]], 1);
    pos[e] = p;
    src_sorted[p] = src[e];
  }
}

// ---------- weight pre-pack kernels (tiny, one-shot) ----------
__global__ void prep_wrel_kernel(const float* __restrict__ W_rel, unsigned short* __restrict__ wrel_pk) {
  int tid = blockIdx.x * blockDim.x + threadIdx.x;   // 8192 total
  if (tid >= 8192) return;
  int j = tid & 7, lane = (tid >> 3) & 63, ks = (tid >> 9) & 1, dg = tid >> 10;
  int k = ks * 32 + 8 * (lane >> 4) + j;
  int col = 16 * dg + (lane & 15);
  wrel_pk[tid] = f2bf(W_rel[k * D_DIM + col]);
}

__global__ void prep_ww_kernel(const float* __restrict__ W_w, unsigned short* __restrict__ ww_pk) {
  int tid = blockIdx.x * blockDim.x + threadIdx.x;   // 65536 total
  if (tid >= 65536) return;
  int j = tid & 7, lane = (tid >> 3) & 63, dg = (tid >> 9) & 7, kc = tid >> 12;
  int c = kc * 32 + 8 * (lane >> 4) + j;
  int d = 16 * dg + (lane & 15);
  ww_pk[tid] = f2bf(W_w[(long long)(c & 127) * 512 + (c >> 7) * 128 + d]);
}

// ---------- node attention partials ----------
__global__ __launch_bounds__(256) void node_att_kernel(
    const float* __restrict__ h, const float* __restrict__ W_att,
    float* __restrict__ a12, int N)
{
  int lane = threadIdx.x & 63;
  int wid = (int)((blockIdx.x * (long long)blockDim.x + threadIdx.x) >> 6);
  if (wid >= N) return;
  const float* hr = &h[(long long)wid * D_DIM];
  float h0 = hr[lane], h1 = hr[64 + lane];
  float p[8];
#pragma unroll
  for (int hd = 0; hd < 4; ++hd) {
    p[hd]     = h0 * W_att[lane * 4 + hd]         + h1 * W_att[(64 + lane) * 4 + hd];
    p[4 + hd] = h0 * W_att[(128 + lane) * 4 + hd] + h1 * W_att[(192 + lane) * 4 + hd];
  }
#pragma unroll
  for (int j = 0; j < 8; ++j) {
    float v = p[j];
#pragma unroll
    for (int off = 32; off; off >>= 1) v += __shfl_xor(v, off);
    if (lane == 0) a12[(long long)wid * 8 + j] = v;
  }
}

// ---------- fused edge pass, MFMA ----------
__global__ __launch_bounds__(256) void edge_mfma_kernel(
    const float* __restrict__ edge_feat, const int* __restrict__ src, const int* __restrict__ dst,
    const unsigned short* __restrict__ wrel_pk, const float* __restrict__ b_rel,
    const float* __restrict__ ln_g, const float* __restrict__ ln_b,
    const float* __restrict__ W_att, const float* __restrict__ b_att,
    const float* __restrict__ a12, const int* __restrict__ pos,
    float* __restrict__ u_sorted, int E)
{
  int l = threadIdx.x & 63;
  int wv = threadIdx.x >> 6;
  long long e0 = (long long)blockIdx.x * 64 + wv * 16;

  s16x8 Bf[8][2];
#pragma unroll
  for (int dg = 0; dg < 8; ++dg)
#pragma unroll
    for (int ks = 0; ks < 2; ++ks)
      Bf[dg][ks] = *reinterpret_cast<const s16x8*>(&wrel_pk[((dg * 2 + ks) * 64 + l) * 8]);

  f32x4 zero4 = {0.f, 0.f, 0.f, 0.f};
  f32x4 acc[8];
#pragma unroll
  for (int dg = 0; dg < 8; ++dg) acc[dg] = zero4;

  long long er = e0 + (l & 15);
  const float* ef = &edge_feat[er * DE_DIM + 8 * (l >> 4)];
  bool erok = (er < E);
#pragma unroll
  for (int ks = 0; ks < 2; ++ks) {
    s16x8 a;
    if (erok) {
      float4 v0 = *reinterpret_cast<const float4*>(&ef[ks * 32]);
      float4 v1 = *reinterpret_cast<const float4*>(&ef[ks * 32 + 4]);
      a[0] = (short)f2bf(v0.x); a[1] = (short)f2bf(v0.y);
      a[2] = (short)f2bf(v0.z); a[3] = (short)f2bf(v0.w);
      a[4] = (short)f2bf(v1.x); a[5] = (short)f2bf(v1.y);
      a[6] = (short)f2bf(v1.z); a[7] = (short)f2bf(v1.w);
    } else {
#pragma unroll
      for (int j = 0; j < 8; ++j) a[j] = 0;
    }
#pragma unroll
    for (int dg = 0; dg < 8; ++dg)
      acc[dg] = __builtin_amdgcn_mfma_f32_16x16x32_bf16(a, Bf[dg][ks], acc[dg], 0, 0, 0);
  }

  int cq = l & 15;
#pragma unroll
  for (int dg = 0; dg < 8; ++dg) {
    float br = b_rel[16 * dg + cq];
#pragma unroll
    for (int i = 0; i < 4; ++i) acc[dg][i] += br;
  }
  float mu[4], rstd[4];
#pragma unroll
  for (int i = 0; i < 4; ++i) {
    float s = 0.f, q = 0.f;
#pragma unroll
    for (int dg = 0; dg < 8; ++dg) { float v = acc[dg][i]; s += v; q += v * v; }
#pragma unroll
    for (int off = 1; off < 16; off <<= 1) { s += __shfl_xor(s, off); q += __shfl_xor(q, off); }
    float m = s * (1.f / 128.f);
    float var = q * (1.f / 128.f) - m * m;
    mu[i] = m;
    rstd[i] = rsqrtf(var + LN_EPS);
  }

  float u[4][4];
#pragma unroll
  for (int i = 0; i < 4; ++i)
#pragma unroll
    for (int hd = 0; hd < 4; ++hd) u[i][hd] = 0.f;
#pragma unroll
  for (int dg = 0; dg < 8; ++dg) {
    int col = 16 * dg + cq;
    float g = ln_g[col], bb = ln_b[col];
    float4 wa = *reinterpret_cast<const float4*>(&W_att[(256 + col) * 4]);
#pragma unroll
    for (int i = 0; i < 4; ++i) {
      float w = (acc[dg][i] - mu[i]) * rstd[i] * g + bb;
      w = fmaxf(w, 0.f);
      u[i][0] = fmaf(w, wa.x, u[i][0]);
      u[i][1] = fmaf(w, wa.y, u[i][1]);
      u[i][2] = fmaf(w, wa.z, u[i][2]);
      u[i][3] = fmaf(w, wa.w, u[i][3]);
    }
  }
#pragma unroll
  for (int i = 0; i < 4; ++i)
#pragma unroll
    for (int hd = 0; hd < 4; ++hd) {
      float v = u[i][hd];
#pragma unroll
      for (int off = 1; off < 16; off <<= 1) v += __shfl_xor(v, off);
      u[i][hd] = v;
    }

  if (cq < 4) {
    float ba = b_att[cq];
#pragma unroll
    for (int i = 0; i < 4; ++i) {
      long long e = e0 + 4 * (l >> 4) + i;
      if (e < E) {
        int sN = src[e], dN = dst[e];
        float v = a12[(long long)dN * 8 + cq] + a12[(long long)sN * 8 + 4 + cq] + u[i][cq] + ba;
        v = (v >= 0.f) ? v : LEAKY * v;
        u_sorted[(long long)pos[e] * 4 + cq] = v;
      }
    }
  }
}

// ---------- per-node segment softmax + gather aggregate (wave per node), t in bf16 ----------
__global__ __launch_bounds__(256) void node_agg_kernel(
    const float* __restrict__ h, const int* __restrict__ src_sorted,
    const float* __restrict__ u_sorted, const int* __restrict__ row_ptr,
    unsigned short* __restrict__ t, int N)
{
  int lane = threadIdx.x & 63;
  int n = (int)((blockIdx.x * (long long)blockDim.x + threadIdx.x) >> 6);
  if (n >= N) return;
  int lo = row_ptr[n], hi = row_ptr[n + 1];
  unsigned short* tb = &t[(long long)n * 512];
  if (lo == hi) {
#pragma unroll
    for (int hd = 0; hd < 4; ++hd) {
      tb[hd * 128 + lane] = 0;
      tb[hd * 128 + 64 + lane] = 0;
    }
    return;
  }
  float m0 = -1e30f, m1 = -1e30f, m2 = -1e30f, m3 = -1e30f;
  for (int p = lo; p < hi; ++p) {
    float4 u = *reinterpret_cast<const float4*>(&u_sorted[(long long)p * 4]);
    m0 = fmaxf(m0, u.x); m1 = fmaxf(m1, u.y);
    m2 = fmaxf(m2, u.z); m3 = fmaxf(m3, u.w);
  }
  float d0 = 0.f, d1 = 0.f, d2 = 0.f, d3 = 0.f;
  float acc[8];
#pragma unroll
  for (int i = 0; i < 8; ++i) acc[i] = 0.f;
  for (int p = lo; p < hi; ++p) {
    float4 u = *reinterpret_cast<const float4*>(&u_sorted[(long long)p * 4]);
    float p0 = __expf(u.x - m0), p1 = __expf(u.y - m1);
    float p2 = __expf(u.z - m2), p3 = __expf(u.w - m3);
    d0 += p0; d1 += p1; d2 += p2; d3 += p3;
    const float* hs = &h[(long long)src_sorted[p] * D_DIM];
    float h0 = hs[lane], h1 = hs[64 + lane];
    acc[0] = fmaf(p0, h0, acc[0]); acc[1] = fmaf(p0, h1, acc[1]);
    acc[2] = fmaf(p1, h0, acc[2]); acc[3] = fmaf(p1, h1, acc[3]);
    acc[4] = fmaf(p2, h0, acc[4]); acc[5] = fmaf(p2, h1, acc[5]);
    acc[6] = fmaf(p3, h0, acc[6]); acc[7] = fmaf(p3, h1, acc[7]);
  }
  float r0 = 1.f / d0, r1 = 1.f / d1, r2 = 1.f / d2, r3 = 1.f / d3;
  tb[0 * 128 + lane] = f2bf(acc[0] * r0); tb[0 * 128 + 64 + lane] = f2bf(acc[1] * r0);
  tb[1 * 128 + lane] = f2bf(acc[2] * r1); tb[1 * 128 + 64 + lane] = f2bf(acc[3] * r1);
  tb[2 * 128 + lane] = f2bf(acc[4] * r2); tb[2 * 128 + 64 + lane] = f2bf(acc[5] * r2);
  tb[3 * 128 + lane] = f2bf(acc[6] * r3); tb[3 * 128 + 64 + lane] = f2bf(acc[7] * r3);
}

// ---------- final node GEMM via MFMA ----------
__global__ __launch_bounds__(256) void node_final_mfma(
    const unsigned short* __restrict__ t_bf, const unsigned short* __restrict__ ww_pk,
    const float* __restrict__ b_w, const int* __restrict__ row_ptr,
    const float* __restrict__ h, const float* __restrict__ prelu_a,
    float* __restrict__ out, int N)
{
  int l = threadIdx.x & 63;
  int wv = threadIdx.x >> 6;
  int base = blockIdx.x * 128 + wv * 32;

  f32x4 zero4 = {0.f, 0.f, 0.f, 0.f};
  f32x4 acc[2][8];
#pragma unroll
  for (int rg = 0; rg < 2; ++rg)
#pragma unroll
    for (int dg = 0; dg < 8; ++dg) acc[rg][dg] = zero4;

  s16x8 azero;
#pragma unroll
  for (int j = 0; j < 8; ++j) azero[j] = 0;

  for (int kc = 0; kc < 16; ++kc) {
    s16x8 a[2];
#pragma unroll
    for (int rg = 0; rg < 2; ++rg) {
      int row = base + rg * 16 + (l & 15);
      a[rg] = (row < N)
        ? *reinterpret_cast<const s16x8*>(&t_bf[(long long)row * 512 + kc * 32 + 8 * (l >> 4)])
        : azero;
    }
#pragma unroll
    for (int dg = 0; dg < 8; ++dg) {
      s16x8 b = *reinterpret_cast<const s16x8*>(&ww_pk[((long long)(kc * 8 + dg) * 64 + l) * 8]);
      acc[0][dg] = __builtin_amdgcn_mfma_f32_16x16x32_bf16(a[0], b, acc[0][dg], 0, 0, 0);
      acc[1][dg] = __builtin_amdgcn_mfma_f32_16x16x32_bf16(a[1], b, acc[1][dg], 0, 0, 0);
    }
  }

  float pa = prelu_a[0];
  int cq = l & 15;
  float bs[8];
#pragma unroll
  for (int dg = 0; dg < 8; ++dg) {
    int col = 16 * dg + cq;
    bs[dg] = b_w[col] + b_w[128 + col] + b_w[256 + col] + b_w[384 + col];
  }
#pragma unroll
  for (int rg = 0; rg < 2; ++rg)
#pragma unroll
    for (int i = 0; i < 4; ++i) {
      int row = base + rg * 16 + 4 * (l >> 4) + i;
      if (row >= N) continue;
      bool has = row_ptr[row + 1] > row_ptr[row];
#pragma unroll
      for (int dg = 0; dg < 8; ++dg) {
        int col = 16 * dg + cq;
        float v = (acc[rg][dg][i] + bs[dg]) * 0.25f;
        v = (v >= 0.f) ? v : pa * v;
        if (!has) v = h[(long long)row * 128 + col];
        out[(long long)row * 128 + col] = v;
      }
    }
}

extern "C" void kernel_launch(void* const* d_in, const int* in_sizes, int n_in,
                              void* d_out, int out_size, void* d_ws, size_t ws_size,
                              hipStream_t stream)
{
  const float* h         = (const float*)d_in[0];
  const float* edge_feat = (const float*)d_in[1];
  const int*   src       = (const int*)d_in[2];
  const int*   dst       = (const int*)d_in[3];
  const float* W_rel     = (const float*)d_in[4];
  const float* b_rel     = (const float*)d_in[5];
  const float* ln_g      = (const float*)d_in[6];
  const float* ln_b      = (const float*)d_in[7];
  const float* W_att     = (const float*)d_in[8];
  const float* b_att     = (const float*)d_in[9];
  const float* W_w       = (const float*)d_in[10];
  const float* b_w       = (const float*)d_in[11];
  const float* prelu_a   = (const float*)d_in[12];

  int N = in_sizes[0] / D_DIM;
  int E = in_sizes[2];
  int nb = (N + 1023) / 1024;

  char* ws = (char*)d_ws;
  size_t off = 0;
  unsigned short* t_bf    = (unsigned short*)(ws + off); off += (size_t)N * 512 * 2;
  float* u_sorted         = (float*)(ws + off);          off += (size_t)E * 4 * 4;
  float* a12              = (float*)(ws + off);          off += (size_t)N * 8 * 4;
  int*   row_ptr          = (int*)(ws + off);            off += (size_t)(N + 1) * 4;
  int*   cnt              = (int*)(ws + off);            off += (size_t)N * 4;
  int*   cursor           = (int*)(ws + off);            off += (size_t)N * 4;
  int*   pos              = (int*)(ws + off);            off += (size_t)E * 4;
  int*   src_sorted       = (int*)(ws + off);            off += (size_t)E * 4;
  unsigned short* wrel_pk = (unsigned short*)(ws + off); off += 8192 * 2;
  unsigned short* ww_pk   = (unsigned short*)(ws + off); off += 65536 * 2;
  int*   bsum             = (int*)(ws + off);            off += 64 * 4;
  int*   boff             = (int*)(ws + off);            off += 64 * 4;

  hipMemsetAsync(cnt, 0, (size_t)N * 4, stream);
  hist_kernel<<<(E + 255) / 256, 256, 0, stream>>>(dst, cnt, E);
  scan1_kernel<<<nb, 256, 0, stream>>>(cnt, bsum, N);
  scan2_kernel<<<1, 64, 0, stream>>>(bsum, boff, &row_ptr[N], nb);
  scan3_kernel<<<nb, 256, 0, stream>>>(cnt, boff, row_ptr, cursor, N);
  scatter_kernel<<<(E + 255) / 256, 256, 0, stream>>>(src, dst, cursor, pos, src_sorted, E);
  prep_wrel_kernel<<<32, 256, 0, stream>>>(W_rel, wrel_pk);
  prep_ww_kernel<<<256, 256, 0, stream>>>(W_w, ww_pk);
  node_att_kernel<<<(N * 64 + 255) / 256, 256, 0, stream>>>(h, W_att, a12, N);
  edge_mfma_kernel<<<(E + 63) / 64, 256, 0, stream>>>(edge_feat, src, dst, wrel_pk, b_rel,
                                                      ln_g, ln_b, W_att, b_att, a12, pos,
                                                      u_sorted, E);
  node_agg_kernel<<<(int)(((long long)N * 64 + 255) / 256), 256, 0, stream>>>(
      h, src_sorted, u_sorted, row_ptr, t_bf, N);
  node_final_mfma<<<(N + 127) / 128, 256, 0, stream>>>(t_bf, ww_pk, b_w, row_ptr, h, prelu_a,
                                                       (float*)d_out, N);
}